// Round 18
// baseline (1788.632 us; speedup 1.0000x reference)
//
#include <hip/hip_runtime.h>
#include <stdint.h>

// Problem constants
#define T_   512
#define B_   64
#define DIN  1024
#define HID  512
#define G3   1536     // 3*HID
#define NC   3072     // both dirs of gates
#define MROWS 32768   // T_*B_
#define RWGS 128      // recur workgroups in fused kernel

typedef __bf16 bf16;
typedef __bf16 bf16x8 __attribute__((ext_vector_type(8)));
typedef float  f32x4  __attribute__((ext_vector_type(4)));

#define GLOBAL_AS __attribute__((address_space(1)))
#define LDS_AS    __attribute__((address_space(3)))

#define LDT(p)   __hip_atomic_load((p), __ATOMIC_RELAXED, __HIP_MEMORY_SCOPE_AGENT)
#define LDT32(p) __hip_atomic_load((p), __ATOMIC_RELAXED, __HIP_MEMORY_SCOPE_AGENT)

__device__ __forceinline__ uint16_t f2bf_bits(float x){
  union{float f; uint32_t u;} v; v.f = x;
  uint32_t u = v.u;
  u += 0x7FFFu + ((u >> 16) & 1u);   // round-to-nearest-even
  return (uint16_t)(u >> 16);
}
__device__ __forceinline__ float bf2f_bits(uint16_t h){
  union{uint32_t u; float f;} v; v.u = ((uint32_t)h) << 16;
  return v.f;
}
__device__ __forceinline__ float sig_f(float x){
  return 1.f/(1.f + __expf(-x));
}
__device__ __forceinline__ float tanh_f(float x){
  return 1.f - 2.f/(1.f + __expf(2.f*x));
}
__device__ __forceinline__ bf16x8 as_bf16x8(uint4 u){
  union{uint4 a; bf16x8 b;} c; c.a = u; return c.b;
}

// ---------------------------------------------------------------- converts
__global__ void k_conv_emb(const float* __restrict__ src, uint16_t* __restrict__ dst, long n8){
  long i = (long)blockIdx.x*blockDim.x + threadIdx.x;
  if(i >= n8) return;
  const float4* s = (const float4*)src;
  float4 a = s[i*2], b = s[i*2+1];
  uint32_t p0 = (uint32_t)f2bf_bits(a.x) | ((uint32_t)f2bf_bits(a.y) << 16);
  uint32_t p1 = (uint32_t)f2bf_bits(a.z) | ((uint32_t)f2bf_bits(a.w) << 16);
  uint32_t p2 = (uint32_t)f2bf_bits(b.x) | ((uint32_t)f2bf_bits(b.y) << 16);
  uint32_t p3 = (uint32_t)f2bf_bits(b.z) | ((uint32_t)f2bf_bits(b.w) << 16);
  ((uint4*)dst)[i] = make_uint4(p0,p1,p2,p3);
}

__global__ void k_conv_wcat(const float* __restrict__ wf, const float* __restrict__ wb, uint16_t* __restrict__ dst, int n){
  int i = blockIdx.x*256 + threadIdx.x;
  if(i >= n) return;
  float v = (i < G3*DIN) ? wf[i] : wb[i - G3*DIN];
  dst[i] = f2bf_bits(v);
}

__global__ void k_conv_awt(const float* __restrict__ aw, uint16_t* __restrict__ dst, int n){
  int i = blockIdx.x*256 + threadIdx.x;
  if(i >= n) return;
  int e = i >> 10, d = i & 1023;
  dst[i] = f2bf_bits(aw[d*1024 + e]);   // transpose: awT[e][d]
}

// W_hh -> bf16, member-sliced, chunk-XOR-pre-swizzled (same layout as r6-r16).
__global__ void k_conv_whh(const float* __restrict__ wf, const float* __restrict__ wb, uint4* __restrict__ wmem){
  int idx = blockIdx.x*256 + threadIdx.x;   // 196608 total
  if(idx >= 2*16*96*64) return;
  int c  = idx & 63;
  int t2 = idx >> 6;
  int lc = t2 % 96;
  int t3 = t2 / 96;
  int member = t3 & 15, dir = t3 >> 4;
  int ct = lc >> 4, rr = lc & 15;
  int gcol = (ct >> 1)*512 + member*32 + (ct & 1)*16 + rr;
  int csrc = c ^ (lc & 7);
  const float* src = (dir ? wb : wf) + (size_t)gcol*512 + csrc*8;
  float4 f0 = *(const float4*)src;
  float4 f1 = *(const float4*)(src + 4);
  uint32_t p0 = (uint32_t)f2bf_bits(f0.x) | ((uint32_t)f2bf_bits(f0.y) << 16);
  uint32_t p1 = (uint32_t)f2bf_bits(f0.z) | ((uint32_t)f2bf_bits(f0.w) << 16);
  uint32_t p2 = (uint32_t)f2bf_bits(f1.x) | ((uint32_t)f2bf_bits(f1.y) << 16);
  uint32_t p3 = (uint32_t)f2bf_bits(f1.z) | ((uint32_t)f2bf_bits(f1.w) << 16);
  wmem[idx] = make_uint4(p0,p1,p2,p3);
}

// ---------------------------------------------------------------- fused: xp-GEMM producers + recurrence consumers
// Blocks [0,128): recurrence (r13-proven tag-in-data protocol, + xctr panel gate).
// Blocks [128, 128+6144): 128x128 GEMM tiles computing xp = emb @ Wcat^T + bias into the
// blocked layout via LDS-transpose epilogue, written as agent-scope u64 atomic stores
// (LLC-visible), then panel counter increment after barrier drain. Panels ordered
// outside-in (speed only; correctness is poll-gated).
__global__ __launch_bounds__(768)
void k_fused(const uint16_t* __restrict__ A, const uint16_t* __restrict__ Bw,
             const float* __restrict__ bihf, const float* __restrict__ bihb,
             uint16_t* __restrict__ xp, unsigned* __restrict__ xctr,
             const uint4* __restrict__ wmem,
             const float* __restrict__ bhhf, const float* __restrict__ bhhb,
             unsigned long long* __restrict__ tagbuf,
             uint16_t* __restrict__ f_out)
{
  __shared__ __align__(16) uint16_t smem[16384];   // 32 KB shared by both roles
  int tid = threadIdx.x;

  if(blockIdx.x >= RWGS){
    // ======================= GEMM producer =======================
    const int K = 1024;
    int g = blockIdx.x - RWGS;
    int bn = g % 24;
    int i  = g / 24;
    int bm = (i & 1) ? (255 - (i >> 1)) : (i >> 1);   // outside-in panel order
    int lane = tid & 63, wid = tid >> 6;
    int wm = wid >> 1, wn = wid & 1;
    int rowBase = bm*128, colBase = bn*128;
    int rg = lane >> 4, rr = lane & 15;

    auto stage = [&](int buf, int kt){
      if(tid < 256){
        #pragma unroll
        for(int i2=0;i2<2;i2++){
          int e = (i2*256 + tid)*8;
          int r = e >> 5, c = e & 31;
          __builtin_amdgcn_global_load_lds((const GLOBAL_AS void*)(A + (size_t)(rowBase + r)*K + kt*32 + c),
                                           (LDS_AS void*)&smem[buf*4096 + e], 16, 0, 0);
        }
        #pragma unroll
        for(int i2=0;i2<2;i2++){
          int e = (i2*256 + tid)*8;
          int r = e >> 5, c = e & 31;
          __builtin_amdgcn_global_load_lds((const GLOBAL_AS void*)(Bw + (size_t)(colBase + r)*K + kt*32 + c),
                                           (LDS_AS void*)&smem[8192 + buf*4096 + e], 16, 0, 0);
        }
      }
    };

    f32x4 acc[4][4];
    #pragma unroll
    for(int mi=0;mi<4;mi++)
      #pragma unroll
      for(int ni=0;ni<4;ni++) acc[mi][ni] = (f32x4){0.f,0.f,0.f,0.f};

    stage(0, 0);
    __syncthreads();
    for(int kt=0; kt<32; kt++){
      int buf = kt & 1;
      if(kt+1 < 32) stage(buf^1, kt+1);
      if(tid < 256){
        bf16x8 af[4], bfv[4];
        #pragma unroll
        for(int mi=0;mi<4;mi++)
          af[mi] = *(const bf16x8*)&smem[buf*4096 + (wm*64 + mi*16 + rr)*32 + rg*8];
        #pragma unroll
        for(int ni=0;ni<4;ni++)
          bfv[ni] = *(const bf16x8*)&smem[8192 + buf*4096 + (wn*64 + ni*16 + rr)*32 + rg*8];
        #pragma unroll
        for(int mi=0;mi<4;mi++)
          #pragma unroll
          for(int ni=0;ni<4;ni++)
            acc[mi][ni] = __builtin_amdgcn_mfma_f32_16x16x32_bf16(af[mi], bfv[ni], acc[mi][ni], 0,0,0);
      }
      __syncthreads();
    }

    // epilogue: bias + store tile to LDS [128][128] bf16 (reuses staging space)
    if(tid < 256){
      #pragma unroll
      for(int ni=0;ni<4;ni++){
        int col = colBase + wn*64 + ni*16 + rr;
        float bv = (col < G3) ? bihf[col] : bihb[col - G3];
        int lc = wn*64 + ni*16 + rr;
        #pragma unroll
        for(int mi=0;mi<4;mi++){
          int row = wm*64 + mi*16 + rg*4;
          #pragma unroll
          for(int r=0;r<4;r++)
            smem[(row+r)*128 + lc] = f2bf_bits(acc[mi][ni][r] + bv);
        }
      }
    }
    __syncthreads();

    // coalesced u64 agent-scope stores into blocked xp layout
    // chunk = 1KB = [16 rows][32 cols] bf16 = 128 u64 (16 rows x 8 u64/row)
    int dircol = (colBase >= G3) ? 1 : 0;
    int cm0 = colBase - dircol*G3;
    int gg  = cm0 >> 9;
    int mem0 = (cm0 & 511) >> 5;
    if(tid < 512){
      #pragma unroll
      for(int k=0;k<8;k++){
        int v = tid*8 + k;         // 0..4095
        int chunk = v >> 7;        // 0..31 : (tt_l, bgx, mem_l)
        int off = v & 127;         // u64 within 1KB chunk
        int tt_l = chunk >> 4, bgx = (chunk >> 2) & 3, mem_l = chunk & 3;
        int row16 = off >> 3, cq = off & 7;
        int lrow = tt_l*64 + bgx*16 + row16;
        int lcol = mem_l*32 + cq*4;
        unsigned long long val = *(const unsigned long long*)&smem[lrow*128 + lcol];
        size_t cb = ((((size_t)(dircol*512 + 2*bm + tt_l)*4 + bgx)*16 + (mem0 + mem_l))*3 + gg)*512;
        __hip_atomic_store((unsigned long long*)(xp + cb) + off, val,
                           __ATOMIC_RELAXED, __HIP_MEMORY_SCOPE_AGENT);
      }
    }
    __syncthreads();   // drains vmcnt: stores acked at LLC
    if(tid == 0)
      __hip_atomic_fetch_add(&xctr[bm], 1u, __ATOMIC_RELAXED, __HIP_MEMORY_SCOPE_AGENT);
    return;
  }

  // ======================= recurrence consumer =======================
  uint16_t* hl = smem;                       // 16 KB, chunk-XOR swizzled
  float*    ghl = (float*)(smem + 8192);     // 12.75 KB

  int bid = blockIdx.x;
  int dir = bid & 1, bg = (bid >> 1) & 3, member = bid >> 3;
  int jb = member*32;
  int lane = tid & 63, w = tid >> 6;
  int rr = lane & 15, rg = lane >> 4;
  int ct = w >> 1, kh = w & 1;

  // W fragments -> registers (8 x 16B per lane, loop-invariant)
  const uint4* wsl = wmem + (size_t)(dir*16 + member)*6144 + (ct*16 + rr)*64;
  int xm = rr & 7;
  uint4 wu0 = wsl[(kh*32 +  0 + rg) ^ xm];
  uint4 wu1 = wsl[(kh*32 +  4 + rg) ^ xm];
  uint4 wu2 = wsl[(kh*32 +  8 + rg) ^ xm];
  uint4 wu3 = wsl[(kh*32 + 12 + rg) ^ xm];
  uint4 wu4 = wsl[(kh*32 + 16 + rg) ^ xm];
  uint4 wu5 = wsl[(kh*32 + 20 + rg) ^ xm];
  uint4 wu6 = wsl[(kh*32 + 24 + rg) ^ xm];
  uint4 wu7 = wsl[(kh*32 + 28 + rg) ^ xm];
  asm volatile("" :: "v"(wu0.x), "v"(wu0.y), "v"(wu0.z), "v"(wu0.w),
                     "v"(wu1.x), "v"(wu1.y), "v"(wu1.z), "v"(wu1.w));
  asm volatile("" :: "v"(wu2.x), "v"(wu2.y), "v"(wu2.z), "v"(wu2.w),
                     "v"(wu3.x), "v"(wu3.y), "v"(wu3.z), "v"(wu3.w));
  asm volatile("" :: "v"(wu4.x), "v"(wu4.y), "v"(wu4.z), "v"(wu4.w),
                     "v"(wu5.x), "v"(wu5.y), "v"(wu5.z), "v"(wu5.w));
  asm volatile("" :: "v"(wu6.x), "v"(wu6.y), "v"(wu6.z), "v"(wu6.w),
                     "v"(wu7.x), "v"(wu7.y), "v"(wu7.z), "v"(wu7.w));

  for(int i = tid; i < 2*6*16*17; i += 768) ghl[i] = 0.f;

  int gcol = tid & 31;
  const float* bhh = dir ? bhhb : bhhf;
  float bR = 0.f, bZ = 0.f, bN = 0.f, hprev = 0.f;
  if(tid < 512){
    bR = bhh[jb + gcol];
    bZ = bhh[512 + jb + gcol];
    bN = bhh[1024 + jb + gcol];
  }

  int srow = tid >> 5;
  int sbase = tid & 31;
  int cswz = ((sbase >> 2) ^ (srow & 7));
  int lpos0 = srow*512 + cswz*8 + (sbase & 3)*2;

  __syncthreads();   // ghl zeroed

  // prologue: wait for panel of step 0 (and step 1 — same panel)
  {
    int p0 = (dir ? 511 : 0) >> 1;
    while(LDT32(&xctr[p0]) < 24u) __builtin_amdgcn_s_sleep(2);
  }

  #pragma unroll 1
  for(int t = 0; t < 512; t++){
    int trow = dir ? (511 - t) : t;

    // early-issue next-panel readiness load (verified at step end)
    unsigned xc = 24u;
    int pnext = -1;
    if(t + 2 < 512){
      pnext = (dir ? (511 - (t + 2)) : (t + 2)) >> 1;
      xc = LDT32(&xctr[pnext]);
    }

    // xp loads: 3 coalesced 1KB loads (panel verified 2 steps ago)
    uint16_t xr16 = 0, xz16 = 0, xn16 = 0;
    if(tid < 512){
      const uint16_t* xb = xp + (((((size_t)dir*512 + trow)*4 + bg)*16 + member)*3)*512;
      xr16 = xb[tid];
      xz16 = xb[512 + tid];
      xn16 = xb[1024 + tid];
    }

    if(t > 0 && tid < 512){
      const unsigned long long* tb =
        tagbuf + ((size_t)((dir*2 + ((t-1) & 1))*4 + bg)*16 + srow)*256 + sbase;
      unsigned want = (unsigned)t;
      unsigned long long v0,v1,v2,v3,v4,v5,v6,v7;
      bool ok;
      do {
        v0 = LDT(tb+0);   v1 = LDT(tb+32);  v2 = LDT(tb+64);  v3 = LDT(tb+96);
        v4 = LDT(tb+128); v5 = LDT(tb+160); v6 = LDT(tb+192); v7 = LDT(tb+224);
        ok = ((unsigned)v0 == want) & ((unsigned)v1 == want)
           & ((unsigned)v2 == want) & ((unsigned)v3 == want)
           & ((unsigned)v4 == want) & ((unsigned)v5 == want)
           & ((unsigned)v6 == want) & ((unsigned)v7 == want);
      } while(!ok);
      *(uint32_t*)&hl[lpos0 +   0] = (uint32_t)(v0 >> 32);
      *(uint32_t*)&hl[lpos0 +  64] = (uint32_t)(v1 >> 32);
      *(uint32_t*)&hl[lpos0 + 128] = (uint32_t)(v2 >> 32);
      *(uint32_t*)&hl[lpos0 + 192] = (uint32_t)(v3 >> 32);
      *(uint32_t*)&hl[lpos0 + 256] = (uint32_t)(v4 >> 32);
      *(uint32_t*)&hl[lpos0 + 320] = (uint32_t)(v5 >> 32);
      *(uint32_t*)&hl[lpos0 + 384] = (uint32_t)(v6 >> 32);
      *(uint32_t*)&hl[lpos0 + 448] = (uint32_t)(v7 >> 32);
    }
    __syncthreads();   // (A) hl ready

    if(t > 0){
      f32x4 acc = (f32x4){0.f,0.f,0.f,0.f};
      {
        bf16x8 a0 = *(const bf16x8*)&hl[rr*512 + ((kh*32 +  0 + rg) ^ xm)*8];
        acc = __builtin_amdgcn_mfma_f32_16x16x32_bf16(a0, as_bf16x8(wu0), acc, 0,0,0);
        bf16x8 a1 = *(const bf16x8*)&hl[rr*512 + ((kh*32 +  4 + rg) ^ xm)*8];
        acc = __builtin_amdgcn_mfma_f32_16x16x32_bf16(a1, as_bf16x8(wu1), acc, 0,0,0);
        bf16x8 a2 = *(const bf16x8*)&hl[rr*512 + ((kh*32 +  8 + rg) ^ xm)*8];
        acc = __builtin_amdgcn_mfma_f32_16x16x32_bf16(a2, as_bf16x8(wu2), acc, 0,0,0);
        bf16x8 a3 = *(const bf16x8*)&hl[rr*512 + ((kh*32 + 12 + rg) ^ xm)*8];
        acc = __builtin_amdgcn_mfma_f32_16x16x32_bf16(a3, as_bf16x8(wu3), acc, 0,0,0);
        bf16x8 a4 = *(const bf16x8*)&hl[rr*512 + ((kh*32 + 16 + rg) ^ xm)*8];
        acc = __builtin_amdgcn_mfma_f32_16x16x32_bf16(a4, as_bf16x8(wu4), acc, 0,0,0);
        bf16x8 a5 = *(const bf16x8*)&hl[rr*512 + ((kh*32 + 20 + rg) ^ xm)*8];
        acc = __builtin_amdgcn_mfma_f32_16x16x32_bf16(a5, as_bf16x8(wu5), acc, 0,0,0);
        bf16x8 a6 = *(const bf16x8*)&hl[rr*512 + ((kh*32 + 24 + rg) ^ xm)*8];
        acc = __builtin_amdgcn_mfma_f32_16x16x32_bf16(a6, as_bf16x8(wu6), acc, 0,0,0);
        bf16x8 a7 = *(const bf16x8*)&hl[rr*512 + ((kh*32 + 28 + rg) ^ xm)*8];
        acc = __builtin_amdgcn_mfma_f32_16x16x32_bf16(a7, as_bf16x8(wu7), acc, 0,0,0);
      }
      #pragma unroll
      for(int j = 0; j < 4; j++)
        ghl[((kh*6 + ct)*16 + rg*4 + j)*17 + rr] = acc[j];
    }
    __syncthreads();   // (B) ghl ready (zeros at t==0)

    if(tid < 512){
      int grow = tid >> 5;
      int c16 = gcol >> 4, cc = gcol & 15;
      float gR = ghl[((0 + c16)*16 + grow)*17 + cc] + ghl[((6  + c16)*16 + grow)*17 + cc] + bR;
      float gZ = ghl[((2 + c16)*16 + grow)*17 + cc] + ghl[((8  + c16)*16 + grow)*17 + cc] + bZ;
      float gN = ghl[((4 + c16)*16 + grow)*17 + cc] + ghl[((10 + c16)*16 + grow)*17 + cc] + bN;
      float rv = sig_f(bf2f_bits(xr16) + gR);
      float zv = sig_f(bf2f_bits(xz16) + gZ);
      float nv = tanh_f(bf2f_bits(xn16) + rv*gN);
      float hnew = (1.f - zv)*nv + zv*hprev;
      hprev = hnew;
      unsigned hb = (unsigned)f2bf_bits(hnew);
      unsigned nb = (unsigned)__shfl_down((int)hb, 1);
      if((tid & 1) == 0){
        unsigned pk = hb | (nb << 16);
        int slot = member*16 + (gcol >> 1);
        unsigned long long pv = ((unsigned long long)pk << 32) | (unsigned)(t + 1);
        __hip_atomic_store(
          tagbuf + ((size_t)((dir*2 + (t & 1))*4 + bg)*16 + grow)*256 + slot,
          pv, __ATOMIC_RELAXED, __HIP_MEMORY_SCOPE_AGENT);
        *(unsigned*)&f_out[((size_t)trow*64 + bg*16 + grow)*1024 + dir*512 + jb + gcol] = pk;
      }
    }
    // verify next panel readiness (off critical path when producer is ahead)
    if(pnext >= 0){
      while(xc < 24u){
        __builtin_amdgcn_s_sleep(1);
        xc = LDT32(&xctr[pnext]);
      }
    }
  }
}

// ---------------------------------------------------------------- GEMM: attention, fused tanh + ctx_w dot
__launch_bounds__(256)
__global__ void k_gemm_att(const uint16_t* __restrict__ A, const uint16_t* __restrict__ Bw,
                           const float* __restrict__ attn_b, const float* __restrict__ ctx_w,
                           float* __restrict__ scores_raw)
{
  __shared__ uint16_t lA[2][128*32];
  __shared__ uint16_t lB[2][128*32];
  const int K = 1024;
  int bn = blockIdx.x, bm = blockIdx.y;
  int tid = threadIdx.x;
  int lane = tid & 63, wid = tid >> 6;
  int wm = wid >> 1, wn = wid & 1;
  int rowBase = bm*128, colBase = bn*128;
  int rg = lane >> 4, rr = lane & 15;

  auto stage = [&](int buf, int kt){
    #pragma unroll
    for(int i=0;i<2;i++){
      int e = (i*256 + tid)*8;
      int r = e >> 5, c = e & 31;
      __builtin_amdgcn_global_load_lds((const GLOBAL_AS void*)(A + (size_t)(rowBase + r)*K + kt*32 + c),
                                       (LDS_AS void*)&lA[buf][e], 16, 0, 0);
    }
    #pragma unroll
    for(int i=0;i<2;i++){
      int e = (i*256 + tid)*8;
      int r = e >> 5, c = e & 31;
      __builtin_amdgcn_global_load_lds((const GLOBAL_AS void*)(Bw + (size_t)(colBase + r)*K + kt*32 + c),
                                       (LDS_AS void*)&lB[buf][e], 16, 0, 0);
    }
  };

  f32x4 acc[4][4];
  #pragma unroll
  for(int mi=0;mi<4;mi++)
    #pragma unroll
    for(int ni=0;ni<4;ni++) acc[mi][ni] = (f32x4){0.f,0.f,0.f,0.f};

  stage(0, 0);
  __syncthreads();
  for(int kt=0; kt<32; kt++){
    int buf = kt & 1;
    if(kt+1 < 32) stage(buf^1, kt+1);
    bf16x8 af[4], bfv[4];
    #pragma unroll
    for(int mi=0;mi<4;mi++)
      af[mi] = *(const bf16x8*)&lA[buf][(wm*64 + mi*16 + rr)*32 + rg*8];
    #pragma unroll
    for(int ni=0;ni<4;ni++)
      bfv[ni] = *(const bf16x8*)&lB[buf][(wn*64 + ni*16 + rr)*32 + rg*8];
    #pragma unroll
    for(int mi=0;mi<4;mi++)
      #pragma unroll
      for(int ni=0;ni<4;ni++)
        acc[mi][ni] = __builtin_amdgcn_mfma_f32_16x16x32_bf16(af[mi], bfv[ni], acc[mi][ni], 0,0,0);
    __syncthreads();
  }

  float ab[4], cw[4];
  #pragma unroll
  for(int ni=0;ni<4;ni++){
    int col = colBase + wn*64 + ni*16 + rr;
    ab[ni] = attn_b[col];
    cw[ni] = ctx_w[col];
  }
  #pragma unroll
  for(int mi=0;mi<4;mi++){
    #pragma unroll
    for(int r=0;r<4;r++){
      float part = 0.f;
      #pragma unroll
      for(int ni=0;ni<4;ni++) part += tanhf(acc[mi][ni][r] + ab[ni]) * cw[ni];
      #pragma unroll
      for(int off=1; off<16; off<<=1) part += __shfl_xor(part, off);
      if(rr == 0){
        int row = rowBase + wm*64 + mi*16 + rg*4 + r;
        atomicAdd(&scores_raw[row], part);
      }
    }
  }
}

// ---------------------------------------------------------------- softmax over T per batch
__global__ void k_softmax(const float* __restrict__ scores_raw, float* __restrict__ wsm){
  __shared__ float sv[512];
  __shared__ float red[8];
  int b = blockIdx.x;
  int tid = threadIdx.x;
  float mymax = -1e30f;
  for(int t = tid; t < 512; t += 256){
    float s = tanhf(scores_raw[t*64 + b]);
    sv[t] = s;
    mymax = fmaxf(mymax, s);
  }
  #pragma unroll
  for(int off=1; off<64; off<<=1) mymax = fmaxf(mymax, __shfl_xor(mymax, off));
  if((tid&63)==0) red[tid>>6] = mymax;
  __syncthreads();
  float bmax = fmaxf(fmaxf(red[0],red[1]), fmaxf(red[2],red[3]));
  __syncthreads();
  float mysum = 0.f;
  for(int t = tid; t < 512; t += 256){
    float e = __expf(sv[t] - bmax);
    sv[t] = e;
    mysum += e;
  }
  #pragma unroll
  for(int off=1; off<64; off<<=1) mysum += __shfl_xor(mysum, off);
  if((tid&63)==0) red[tid>>6] = mysum;
  __syncthreads();
  float inv = 1.f/(red[0]+red[1]+red[2]+red[3]);
  for(int t = tid; t < 512; t += 256) wsm[b*512 + t] = sv[t]*inv;
}

// ---------------------------------------------------------------- ctx[b,d] = sum_t w[b,t] f[t,b,d]
__global__ void k_ctx(const uint16_t* __restrict__ f_out, const float* __restrict__ wsm, float* __restrict__ ctx){
  __shared__ float wloc[512];
  int b = blockIdx.x >> 2, chunk = blockIdx.x & 3;
  int tid = threadIdx.x;
  for(int t = tid; t < 512; t += 256) wloc[t] = wsm[b*512 + t];
  __syncthreads();
  int d = chunk*256 + tid;
  float acc = 0.f;
  #pragma unroll 8
  for(int t = 0; t < 512; t++)
    acc += wloc[t] * bf2f_bits(f_out[(size_t)(t*64 + b)*1024 + d]);
  ctx[b*1024 + d] = acc;
}

// ---------------------------------------------------------------- classifier
__global__ void k_cls1(const float* __restrict__ ctx, const float* __restrict__ w1,
                       const float* __restrict__ b1, float* __restrict__ hid){
  int idx = blockIdx.x*256 + threadIdx.x;   // 32768
  int b = idx >> 9, h = idx & 511;
  float acc = b1[h];
  for(int d = 0; d < 1024; d++) acc += ctx[b*1024 + d] * w1[d*512 + h];
  hid[idx] = fmaxf(acc, 0.f);
}

// parallel k_cls2: one block (64 lanes) per output element; 8 elems/lane + shuffle reduce
__global__ void k_cls2(const float* __restrict__ hid, const float* __restrict__ w2,
                       const float* __restrict__ b2, float* __restrict__ out){
  int idx = blockIdx.x;        // 640 outputs
  int b = idx / 10, o = idx % 10;
  int lane = threadIdx.x;      // 64
  float acc = 0.f;
  #pragma unroll
  for(int k = 0; k < 8; k++){
    int h = lane + k*64;
    acc += hid[b*512 + h] * w2[h*10 + o];
  }
  #pragma unroll
  for(int off = 1; off < 64; off <<= 1) acc += __shfl_xor(acc, off);
  if(lane == 0) out[idx] = acc + b2[o];
}

// ---------------------------------------------------------------- launch
extern "C" void kernel_launch(void* const* d_in, const int* in_sizes, int n_in,
                              void* d_out, int out_size, void* d_ws, size_t ws_size,
                              hipStream_t stream)
{
  const float* emb    = (const float*)d_in[1];
  const float* w_ih_f = (const float*)d_in[2];
  const float* w_hh_f = (const float*)d_in[3];
  const float* b_ih_f = (const float*)d_in[4];
  const float* b_hh_f = (const float*)d_in[5];
  const float* w_ih_b = (const float*)d_in[6];
  const float* w_hh_b = (const float*)d_in[7];
  const float* b_ih_b = (const float*)d_in[8];
  const float* b_hh_b = (const float*)d_in[9];
  const float* attn_w = (const float*)d_in[10];
  const float* attn_b = (const float*)d_in[11];
  const float* ctx_w  = (const float*)d_in[12];
  const float* cls_w1 = (const float*)d_in[13];
  const float* cls_b1 = (const float*)d_in[14];
  const float* cls_w2 = (const float*)d_in[15];
  const float* cls_b2 = (const float*)d_in[16];
  float* out = (float*)d_out;

  char* ws = (char*)d_ws;
  size_t off = 0;
  auto alloc = [&](size_t bytes){ void* p = ws + off; off += (bytes + 255) & ~(size_t)255; return p; };
  uint16_t* femb = (uint16_t*)alloc((size_t)MROWS*DIN*2);      // emb bf16, later overlaid by f_out
  uint16_t* wcat = (uint16_t*)alloc((size_t)NC*DIN*2);
  uint16_t* xp   = (uint16_t*)alloc((size_t)MROWS*NC*2);       // blocked layout
  uint16_t* awT  = (uint16_t*)alloc((size_t)1024*1024*2);
  uint4*    wmem = (uint4*)alloc((size_t)2*16*96*64*16);       // 3 MB pre-swizzled W
  unsigned long long* tagbuf = (unsigned long long*)alloc((size_t)2*2*4*16*256*8);  // 1 MB
  unsigned* xctr = (unsigned*)alloc(1024);                     // 256 panel counters
  float* scraw   = (float*)alloc((size_t)MROWS*4);
  float* wsm     = (float*)alloc((size_t)B_*T_*4);
  float* ctx     = (float*)alloc((size_t)B_*1024*4);
  float* hid     = (float*)alloc((size_t)B_*512*4);

  (void)hipMemsetAsync(tagbuf, 0, (size_t)2*2*4*16*256*8, stream);
  (void)hipMemsetAsync(xctr, 0, 1024, stream);
  (void)hipMemsetAsync(scraw, 0, (size_t)MROWS*4, stream);

  k_conv_emb<<<16384, 256, 0, stream>>>(emb, femb, (long)MROWS*DIN/8);
  k_conv_wcat<<<12288, 256, 0, stream>>>(w_ih_f, w_ih_b, wcat, NC*DIN);
  k_conv_awt<<<4096, 256, 0, stream>>>(attn_w, awT, 1024*1024);
  k_conv_whh<<<768, 256, 0, stream>>>(w_hh_f, w_hh_b, wmem);

  k_fused<<<RWGS + 24*256, 768, 0, stream>>>(femb, wcat, b_ih_f, b_ih_b,
                                             xp, xctr, wmem, b_hh_f, b_hh_b,
                                             tagbuf, femb /* = f_out */);

  k_gemm_att<<<dim3(8,256), 256, 0, stream>>>(femb, awT, attn_b, ctx_w, scraw);
  k_softmax<<<64, 256, 0, stream>>>(scraw, wsm);
  k_ctx<<<256, 256, 0, stream>>>(femb, wsm, ctx);
  k_cls1<<<128, 256, 0, stream>>>(ctx, cls_w1, cls_b1, hid);
  k_cls2<<<640, 64, 0, stream>>>(hid, cls_w2, cls_b2, out);
}

// Round 19
// 1480.373 us; speedup vs baseline: 1.2082x; 1.2082x over previous
//
#include <hip/hip_runtime.h>
#include <stdint.h>

// Problem constants
#define T_   512
#define B_   64
#define DIN  1024
#define HID  512
#define G3   1536     // 3*HID
#define NC   3072     // both dirs of gates
#define MROWS 32768   // T_*B_

typedef __bf16 bf16;
typedef __bf16 bf16x8 __attribute__((ext_vector_type(8)));
typedef float  f32x4  __attribute__((ext_vector_type(4)));

#define GLOBAL_AS __attribute__((address_space(1)))
#define LDS_AS    __attribute__((address_space(3)))

#define LDT(p) __hip_atomic_load((p), __ATOMIC_RELAXED, __HIP_MEMORY_SCOPE_AGENT)

__device__ __forceinline__ uint16_t f2bf_bits(float x){
  union{float f; uint32_t u;} v; v.f = x;
  uint32_t u = v.u;
  u += 0x7FFFu + ((u >> 16) & 1u);   // round-to-nearest-even
  return (uint16_t)(u >> 16);
}
__device__ __forceinline__ float bf2f_bits(uint16_t h){
  union{uint32_t u; float f;} v; v.u = ((uint32_t)h) << 16;
  return v.f;
}
__device__ __forceinline__ float sig_f(float x){
  return 1.f/(1.f + __expf(-x));
}
__device__ __forceinline__ float tanh_f(float x){
  return 1.f - 2.f/(1.f + __expf(2.f*x));
}
__device__ __forceinline__ bf16x8 as_bf16x8(uint4 u){
  union{uint4 a; bf16x8 b;} c; c.a = u; return c.b;
}

// ---------------------------------------------------------------- converts
__global__ void k_conv_emb(const float* __restrict__ src, uint16_t* __restrict__ dst, long n8){
  long i = (long)blockIdx.x*blockDim.x + threadIdx.x;
  if(i >= n8) return;
  const float4* s = (const float4*)src;
  float4 a = s[i*2], b = s[i*2+1];
  uint32_t p0 = (uint32_t)f2bf_bits(a.x) | ((uint32_t)f2bf_bits(a.y) << 16);
  uint32_t p1 = (uint32_t)f2bf_bits(a.z) | ((uint32_t)f2bf_bits(a.w) << 16);
  uint32_t p2 = (uint32_t)f2bf_bits(b.x) | ((uint32_t)f2bf_bits(b.y) << 16);
  uint32_t p3 = (uint32_t)f2bf_bits(b.z) | ((uint32_t)f2bf_bits(b.w) << 16);
  ((uint4*)dst)[i] = make_uint4(p0,p1,p2,p3);
}

__global__ void k_conv_wcat(const float* __restrict__ wf, const float* __restrict__ wb, uint16_t* __restrict__ dst, int n){
  int i = blockIdx.x*256 + threadIdx.x;
  if(i >= n) return;
  float v = (i < G3*DIN) ? wf[i] : wb[i - G3*DIN];
  dst[i] = f2bf_bits(v);
}

__global__ void k_conv_awt(const float* __restrict__ aw, uint16_t* __restrict__ dst, int n){
  int i = blockIdx.x*256 + threadIdx.x;
  if(i >= n) return;
  int e = i >> 10, d = i & 1023;
  dst[i] = f2bf_bits(aw[d*1024 + e]);   // transpose: awT[e][d]
}

// W_hh -> bf16, member-sliced, chunk-XOR-pre-swizzled (same layout as r6-r16).
__global__ void k_conv_whh(const float* __restrict__ wf, const float* __restrict__ wb, uint4* __restrict__ wmem){
  int idx = blockIdx.x*256 + threadIdx.x;   // 196608 total
  if(idx >= 2*16*96*64) return;
  int c  = idx & 63;
  int t2 = idx >> 6;
  int lc = t2 % 96;
  int t3 = t2 / 96;
  int member = t3 & 15, dir = t3 >> 4;
  int ct = lc >> 4, rr = lc & 15;
  int gcol = (ct >> 1)*512 + member*32 + (ct & 1)*16 + rr;
  int csrc = c ^ (lc & 7);
  const float* src = (dir ? wb : wf) + (size_t)gcol*512 + csrc*8;
  float4 f0 = *(const float4*)src;
  float4 f1 = *(const float4*)(src + 4);
  uint32_t p0 = (uint32_t)f2bf_bits(f0.x) | ((uint32_t)f2bf_bits(f0.y) << 16);
  uint32_t p1 = (uint32_t)f2bf_bits(f0.z) | ((uint32_t)f2bf_bits(f0.w) << 16);
  uint32_t p2 = (uint32_t)f2bf_bits(f1.x) | ((uint32_t)f2bf_bits(f1.y) << 16);
  uint32_t p3 = (uint32_t)f2bf_bits(f1.z) | ((uint32_t)f2bf_bits(f1.w) << 16);
  wmem[idx] = make_uint4(p0,p1,p2,p3);
}

// ---------------------------------------------------------------- GEMM: xp = emb @ Wcat^T + bias
// OUTPUT BLOCKED for k_recur: xp[dir][t][bg][member][g][16 rows][32 cols] bf16.
// Epilogue: LDS-transpose (validated r18) + coalesced plain u64 stores.
__launch_bounds__(256)
__global__ void k_gemm_xp(const uint16_t* __restrict__ A, const uint16_t* __restrict__ Bw,
                          const float* __restrict__ bihf, const float* __restrict__ bihb,
                          uint16_t* __restrict__ C)
{
  __shared__ __align__(16) uint16_t smem[16384];   // 32 KB: staging (2x8K u16 halves) then tile
  const int K = 1024;
  int bn = blockIdx.x, bm = blockIdx.y;
  int tid = threadIdx.x;
  int lane = tid & 63, wid = tid >> 6;
  int wm = wid >> 1, wn = wid & 1;
  int rowBase = bm*128, colBase = bn*128;
  int rg = lane >> 4, rr = lane & 15;

  auto stage = [&](int buf, int kt){
    #pragma unroll
    for(int i2=0;i2<2;i2++){
      int e = (i2*256 + tid)*8;
      int r = e >> 5, c = e & 31;
      __builtin_amdgcn_global_load_lds((const GLOBAL_AS void*)(A + (size_t)(rowBase + r)*K + kt*32 + c),
                                       (LDS_AS void*)&smem[buf*4096 + e], 16, 0, 0);
    }
    #pragma unroll
    for(int i2=0;i2<2;i2++){
      int e = (i2*256 + tid)*8;
      int r = e >> 5, c = e & 31;
      __builtin_amdgcn_global_load_lds((const GLOBAL_AS void*)(Bw + (size_t)(colBase + r)*K + kt*32 + c),
                                       (LDS_AS void*)&smem[8192 + buf*4096 + e], 16, 0, 0);
    }
  };

  f32x4 acc[4][4];
  #pragma unroll
  for(int mi=0;mi<4;mi++)
    #pragma unroll
    for(int ni=0;ni<4;ni++) acc[mi][ni] = (f32x4){0.f,0.f,0.f,0.f};

  stage(0, 0);
  __syncthreads();
  for(int kt=0; kt<32; kt++){
    int buf = kt & 1;
    if(kt+1 < 32) stage(buf^1, kt+1);
    bf16x8 af[4], bfv[4];
    #pragma unroll
    for(int mi=0;mi<4;mi++)
      af[mi] = *(const bf16x8*)&smem[buf*4096 + (wm*64 + mi*16 + rr)*32 + rg*8];
    #pragma unroll
    for(int ni=0;ni<4;ni++)
      bfv[ni] = *(const bf16x8*)&smem[8192 + buf*4096 + (wn*64 + ni*16 + rr)*32 + rg*8];
    #pragma unroll
    for(int mi=0;mi<4;mi++)
      #pragma unroll
      for(int ni=0;ni<4;ni++)
        acc[mi][ni] = __builtin_amdgcn_mfma_f32_16x16x32_bf16(af[mi], bfv[ni], acc[mi][ni], 0,0,0);
    __syncthreads();
  }

  // epilogue: bias + store tile to LDS [128][128] bf16
  #pragma unroll
  for(int ni=0;ni<4;ni++){
    int col = colBase + wn*64 + ni*16 + rr;
    float bv = (col < G3) ? bihf[col] : bihb[col - G3];
    int lc = wn*64 + ni*16 + rr;
    #pragma unroll
    for(int mi=0;mi<4;mi++){
      int row = wm*64 + mi*16 + rg*4;
      #pragma unroll
      for(int r=0;r<4;r++)
        smem[(row+r)*128 + lc] = f2bf_bits(acc[mi][ni][r] + bv);
    }
  }
  __syncthreads();

  // coalesced plain u64 stores into blocked xp layout
  // chunk = 1KB = [16 rows][32 cols] bf16 = 128 u64 (16 rows x 8 u64/row)
  int dircol = (colBase >= G3) ? 1 : 0;
  int cm0 = colBase - dircol*G3;
  int gg  = cm0 >> 9;
  int mem0 = (cm0 & 511) >> 5;
  #pragma unroll
  for(int k=0;k<16;k++){
    int v = k*256 + tid;       // 0..4095 (lanes consecutive -> contiguous dest)
    int chunk = v >> 7;        // 0..31 : (tt_l, bgx, mem_l)
    int off = v & 127;         // u64 within 1KB chunk
    int tt_l = chunk >> 4, bgx = (chunk >> 2) & 3, mem_l = chunk & 3;
    int row16 = off >> 3, cq = off & 7;
    int lrow = tt_l*64 + bgx*16 + row16;
    int lcol = mem_l*32 + cq*4;
    unsigned long long val = *(const unsigned long long*)&smem[lrow*128 + lcol];
    size_t cb = ((((size_t)(dircol*512 + 2*bm + tt_l)*4 + bgx)*16 + (mem0 + mem_l))*3 + gg)*512;
    *((unsigned long long*)(C + cb) + off) = val;
  }
}

// ---------------------------------------------------------------- GEMM: attention, fused tanh + ctx_w dot
__launch_bounds__(256)
__global__ void k_gemm_att(const uint16_t* __restrict__ A, const uint16_t* __restrict__ Bw,
                           const float* __restrict__ attn_b, const float* __restrict__ ctx_w,
                           float* __restrict__ scores_raw)
{
  __shared__ uint16_t lA[2][128*32];
  __shared__ uint16_t lB[2][128*32];
  const int K = 1024;
  int bn = blockIdx.x, bm = blockIdx.y;
  int tid = threadIdx.x;
  int lane = tid & 63, wid = tid >> 6;
  int wm = wid >> 1, wn = wid & 1;
  int rowBase = bm*128, colBase = bn*128;
  int rg = lane >> 4, rr = lane & 15;

  auto stage = [&](int buf, int kt){
    #pragma unroll
    for(int i=0;i<2;i++){
      int e = (i*256 + tid)*8;
      int r = e >> 5, c = e & 31;
      __builtin_amdgcn_global_load_lds((const GLOBAL_AS void*)(A + (size_t)(rowBase + r)*K + kt*32 + c),
                                       (LDS_AS void*)&lA[buf][e], 16, 0, 0);
    }
    #pragma unroll
    for(int i=0;i<2;i++){
      int e = (i*256 + tid)*8;
      int r = e >> 5, c = e & 31;
      __builtin_amdgcn_global_load_lds((const GLOBAL_AS void*)(Bw + (size_t)(colBase + r)*K + kt*32 + c),
                                       (LDS_AS void*)&lB[buf][e], 16, 0, 0);
    }
  };

  f32x4 acc[4][4];
  #pragma unroll
  for(int mi=0;mi<4;mi++)
    #pragma unroll
    for(int ni=0;ni<4;ni++) acc[mi][ni] = (f32x4){0.f,0.f,0.f,0.f};

  stage(0, 0);
  __syncthreads();
  for(int kt=0; kt<32; kt++){
    int buf = kt & 1;
    if(kt+1 < 32) stage(buf^1, kt+1);
    bf16x8 af[4], bfv[4];
    #pragma unroll
    for(int mi=0;mi<4;mi++)
      af[mi] = *(const bf16x8*)&lA[buf][(wm*64 + mi*16 + rr)*32 + rg*8];
    #pragma unroll
    for(int ni=0;ni<4;ni++)
      bfv[ni] = *(const bf16x8*)&lB[buf][(wn*64 + ni*16 + rr)*32 + rg*8];
    #pragma unroll
    for(int mi=0;mi<4;mi++)
      #pragma unroll
      for(int ni=0;ni<4;ni++)
        acc[mi][ni] = __builtin_amdgcn_mfma_f32_16x16x32_bf16(af[mi], bfv[ni], acc[mi][ni], 0,0,0);
    __syncthreads();
  }

  float ab[4], cw[4];
  #pragma unroll
  for(int ni=0;ni<4;ni++){
    int col = colBase + wn*64 + ni*16 + rr;
    ab[ni] = attn_b[col];
    cw[ni] = ctx_w[col];
  }
  #pragma unroll
  for(int mi=0;mi<4;mi++){
    #pragma unroll
    for(int r=0;r<4;r++){
      float part = 0.f;
      #pragma unroll
      for(int ni=0;ni<4;ni++) part += tanhf(acc[mi][ni][r] + ab[ni]) * cw[ni];
      #pragma unroll
      for(int off=1; off<16; off<<=1) part += __shfl_xor(part, off);
      if(rr == 0){
        int row = rowBase + wm*64 + mi*16 + rg*4 + r;
        atomicAdd(&scores_raw[row], part);
      }
    }
  }
}

// ---------------------------------------------------------------- recurrence (r13-proven): tag-in-data + W in registers.
__launch_bounds__(768, 3)
__global__ void k_recur(const uint16_t* __restrict__ xp,     // blocked [dir][T][bg][member][3][16][32]
                        const uint4* __restrict__ wmem,      // pre-swizzled W slices
                        const float* __restrict__ bhhf, const float* __restrict__ bhhb,
                        unsigned long long* __restrict__ tagbuf,
                        uint16_t* __restrict__ f_out)
{
  __shared__ uint16_t hl[16*512];        // 16 KB, chunk-XOR swizzled
  __shared__ float    ghl[2*6*16*17];    // 12.75 KB

  int bid = blockIdx.x;
  int dir = bid & 1, bg = (bid >> 1) & 3, member = bid >> 3;
  int jb = member*32;
  int tid = threadIdx.x;
  int lane = tid & 63, w = tid >> 6;
  int rr = lane & 15, rg = lane >> 4;
  int ct = w >> 1, kh = w & 1;

  // W fragments -> registers (8 x 16B per lane, loop-invariant)
  const uint4* wsl = wmem + (size_t)(dir*16 + member)*6144 + (ct*16 + rr)*64;
  int xm = rr & 7;
  uint4 wu0 = wsl[(kh*32 +  0 + rg) ^ xm];
  uint4 wu1 = wsl[(kh*32 +  4 + rg) ^ xm];
  uint4 wu2 = wsl[(kh*32 +  8 + rg) ^ xm];
  uint4 wu3 = wsl[(kh*32 + 12 + rg) ^ xm];
  uint4 wu4 = wsl[(kh*32 + 16 + rg) ^ xm];
  uint4 wu5 = wsl[(kh*32 + 20 + rg) ^ xm];
  uint4 wu6 = wsl[(kh*32 + 24 + rg) ^ xm];
  uint4 wu7 = wsl[(kh*32 + 28 + rg) ^ xm];
  asm volatile("" :: "v"(wu0.x), "v"(wu0.y), "v"(wu0.z), "v"(wu0.w),
                     "v"(wu1.x), "v"(wu1.y), "v"(wu1.z), "v"(wu1.w));
  asm volatile("" :: "v"(wu2.x), "v"(wu2.y), "v"(wu2.z), "v"(wu2.w),
                     "v"(wu3.x), "v"(wu3.y), "v"(wu3.z), "v"(wu3.w));
  asm volatile("" :: "v"(wu4.x), "v"(wu4.y), "v"(wu4.z), "v"(wu4.w),
                     "v"(wu5.x), "v"(wu5.y), "v"(wu5.z), "v"(wu5.w));
  asm volatile("" :: "v"(wu6.x), "v"(wu6.y), "v"(wu6.z), "v"(wu6.w),
                     "v"(wu7.x), "v"(wu7.y), "v"(wu7.z), "v"(wu7.w));

  for(int i = tid; i < 2*6*16*17; i += 768) ghl[i] = 0.f;

  int gcol = tid & 31;
  const float* bhh = dir ? bhhb : bhhf;
  float bR = 0.f, bZ = 0.f, bN = 0.f, hprev = 0.f;
  if(tid < 512){
    bR = bhh[jb + gcol];
    bZ = bhh[512 + jb + gcol];
    bN = bhh[1024 + jb + gcol];
  }

  int srow = tid >> 5;
  int sbase = tid & 31;
  int cswz = ((sbase >> 2) ^ (srow & 7));
  int lpos0 = srow*512 + cswz*8 + (sbase & 3)*2;

  __syncthreads();   // ghl zeroed

  #pragma unroll 1
  for(int t = 0; t < 512; t++){
    int trow = dir ? (511 - t) : t;

    uint16_t xr16 = 0, xz16 = 0, xn16 = 0;
    if(tid < 512){
      const uint16_t* xb = xp + (((((size_t)dir*512 + trow)*4 + bg)*16 + member)*3)*512;
      xr16 = xb[tid];
      xz16 = xb[512 + tid];
      xn16 = xb[1024 + tid];
    }

    if(t > 0 && tid < 512){
      const unsigned long long* tb =
        tagbuf + ((size_t)((dir*2 + ((t-1) & 1))*4 + bg)*16 + srow)*256 + sbase;
      unsigned want = (unsigned)t;
      unsigned long long v0,v1,v2,v3,v4,v5,v6,v7;
      bool ok;
      do {
        v0 = LDT(tb+0);   v1 = LDT(tb+32);  v2 = LDT(tb+64);  v3 = LDT(tb+96);
        v4 = LDT(tb+128); v5 = LDT(tb+160); v6 = LDT(tb+192); v7 = LDT(tb+224);
        ok = ((unsigned)v0 == want) & ((unsigned)v1 == want)
           & ((unsigned)v2 == want) & ((unsigned)v3 == want)
           & ((unsigned)v4 == want) & ((unsigned)v5 == want)
           & ((unsigned)v6 == want) & ((unsigned)v7 == want);
      } while(!ok);
      *(uint32_t*)&hl[lpos0 +   0] = (uint32_t)(v0 >> 32);
      *(uint32_t*)&hl[lpos0 +  64] = (uint32_t)(v1 >> 32);
      *(uint32_t*)&hl[lpos0 + 128] = (uint32_t)(v2 >> 32);
      *(uint32_t*)&hl[lpos0 + 192] = (uint32_t)(v3 >> 32);
      *(uint32_t*)&hl[lpos0 + 256] = (uint32_t)(v4 >> 32);
      *(uint32_t*)&hl[lpos0 + 320] = (uint32_t)(v5 >> 32);
      *(uint32_t*)&hl[lpos0 + 384] = (uint32_t)(v6 >> 32);
      *(uint32_t*)&hl[lpos0 + 448] = (uint32_t)(v7 >> 32);
    }
    __syncthreads();   // (A) hl ready

    if(t > 0){
      f32x4 acc = (f32x4){0.f,0.f,0.f,0.f};
      {
        bf16x8 a0 = *(const bf16x8*)&hl[rr*512 + ((kh*32 +  0 + rg) ^ xm)*8];
        acc = __builtin_amdgcn_mfma_f32_16x16x32_bf16(a0, as_bf16x8(wu0), acc, 0,0,0);
        bf16x8 a1 = *(const bf16x8*)&hl[rr*512 + ((kh*32 +  4 + rg) ^ xm)*8];
        acc = __builtin_amdgcn_mfma_f32_16x16x32_bf16(a1, as_bf16x8(wu1), acc, 0,0,0);
        bf16x8 a2 = *(const bf16x8*)&hl[rr*512 + ((kh*32 +  8 + rg) ^ xm)*8];
        acc = __builtin_amdgcn_mfma_f32_16x16x32_bf16(a2, as_bf16x8(wu2), acc, 0,0,0);
        bf16x8 a3 = *(const bf16x8*)&hl[rr*512 + ((kh*32 + 12 + rg) ^ xm)*8];
        acc = __builtin_amdgcn_mfma_f32_16x16x32_bf16(a3, as_bf16x8(wu3), acc, 0,0,0);
        bf16x8 a4 = *(const bf16x8*)&hl[rr*512 + ((kh*32 + 16 + rg) ^ xm)*8];
        acc = __builtin_amdgcn_mfma_f32_16x16x32_bf16(a4, as_bf16x8(wu4), acc, 0,0,0);
        bf16x8 a5 = *(const bf16x8*)&hl[rr*512 + ((kh*32 + 20 + rg) ^ xm)*8];
        acc = __builtin_amdgcn_mfma_f32_16x16x32_bf16(a5, as_bf16x8(wu5), acc, 0,0,0);
        bf16x8 a6 = *(const bf16x8*)&hl[rr*512 + ((kh*32 + 24 + rg) ^ xm)*8];
        acc = __builtin_amdgcn_mfma_f32_16x16x32_bf16(a6, as_bf16x8(wu6), acc, 0,0,0);
        bf16x8 a7 = *(const bf16x8*)&hl[rr*512 + ((kh*32 + 28 + rg) ^ xm)*8];
        acc = __builtin_amdgcn_mfma_f32_16x16x32_bf16(a7, as_bf16x8(wu7), acc, 0,0,0);
      }
      #pragma unroll
      for(int j = 0; j < 4; j++)
        ghl[((kh*6 + ct)*16 + rg*4 + j)*17 + rr] = acc[j];
    }
    __syncthreads();   // (B) ghl ready (zeros at t==0)

    if(tid < 512){
      int grow = tid >> 5;
      int c16 = gcol >> 4, cc = gcol & 15;
      float gR = ghl[((0 + c16)*16 + grow)*17 + cc] + ghl[((6  + c16)*16 + grow)*17 + cc] + bR;
      float gZ = ghl[((2 + c16)*16 + grow)*17 + cc] + ghl[((8  + c16)*16 + grow)*17 + cc] + bZ;
      float gN = ghl[((4 + c16)*16 + grow)*17 + cc] + ghl[((10 + c16)*16 + grow)*17 + cc] + bN;
      float rv = sig_f(bf2f_bits(xr16) + gR);
      float zv = sig_f(bf2f_bits(xz16) + gZ);
      float nv = tanh_f(bf2f_bits(xn16) + rv*gN);
      float hnew = (1.f - zv)*nv + zv*hprev;
      hprev = hnew;
      unsigned hb = (unsigned)f2bf_bits(hnew);
      unsigned nb = (unsigned)__shfl_down((int)hb, 1);
      if((tid & 1) == 0){
        unsigned pk = hb | (nb << 16);
        int slot = member*16 + (gcol >> 1);
        unsigned long long pv = ((unsigned long long)pk << 32) | (unsigned)(t + 1);
        __hip_atomic_store(
          tagbuf + ((size_t)((dir*2 + (t & 1))*4 + bg)*16 + grow)*256 + slot,
          pv, __ATOMIC_RELAXED, __HIP_MEMORY_SCOPE_AGENT);
        *(unsigned*)&f_out[((size_t)trow*64 + bg*16 + grow)*1024 + dir*512 + jb + gcol] = pk;
      }
    }
    // no drain barrier: tag carries sync; next iteration's barriers cover LDS hazards
  }
}

// ---------------------------------------------------------------- softmax over T per batch
__global__ void k_softmax(const float* __restrict__ scores_raw, float* __restrict__ wsm){
  __shared__ float sv[512];
  __shared__ float red[8];
  int b = blockIdx.x;
  int tid = threadIdx.x;
  float mymax = -1e30f;
  for(int t = tid; t < 512; t += 256){
    float s = tanhf(scores_raw[t*64 + b]);
    sv[t] = s;
    mymax = fmaxf(mymax, s);
  }
  #pragma unroll
  for(int off=1; off<64; off<<=1) mymax = fmaxf(mymax, __shfl_xor(mymax, off));
  if((tid&63)==0) red[tid>>6] = mymax;
  __syncthreads();
  float bmax = fmaxf(fmaxf(red[0],red[1]), fmaxf(red[2],red[3]));
  __syncthreads();
  float mysum = 0.f;
  for(int t = tid; t < 512; t += 256){
    float e = __expf(sv[t] - bmax);
    sv[t] = e;
    mysum += e;
  }
  #pragma unroll
  for(int off=1; off<64; off<<=1) mysum += __shfl_xor(mysum, off);
  if((tid&63)==0) red[tid>>6] = mysum;
  __syncthreads();
  float inv = 1.f/(red[0]+red[1]+red[2]+red[3]);
  for(int t = tid; t < 512; t += 256) wsm[b*512 + t] = sv[t]*inv;
}

// ---------------------------------------------------------------- ctx[b,d] = sum_t w[b,t] f[t,b,d]
__global__ void k_ctx(const uint16_t* __restrict__ f_out, const float* __restrict__ wsm, float* __restrict__ ctx){
  __shared__ float wloc[512];
  int b = blockIdx.x >> 2, chunk = blockIdx.x & 3;
  int tid = threadIdx.x;
  for(int t = tid; t < 512; t += 256) wloc[t] = wsm[b*512 + t];
  __syncthreads();
  int d = chunk*256 + tid;
  float acc = 0.f;
  #pragma unroll 8
  for(int t = 0; t < 512; t++)
    acc += wloc[t] * bf2f_bits(f_out[(size_t)(t*64 + b)*1024 + d]);
  ctx[b*1024 + d] = acc;
}

// ---------------------------------------------------------------- classifier
__global__ void k_cls1(const float* __restrict__ ctx, const float* __restrict__ w1,
                       const float* __restrict__ b1, float* __restrict__ hid){
  int idx = blockIdx.x*256 + threadIdx.x;   // 32768
  int b = idx >> 9, h = idx & 511;
  float acc = b1[h];
  for(int d = 0; d < 1024; d++) acc += ctx[b*1024 + d] * w1[d*512 + h];
  hid[idx] = fmaxf(acc, 0.f);
}

// parallel k_cls2: one block (64 lanes) per output element; 8 elems/lane + shuffle reduce
__global__ void k_cls2(const float* __restrict__ hid, const float* __restrict__ w2,
                       const float* __restrict__ b2, float* __restrict__ out){
  int idx = blockIdx.x;        // 640 outputs
  int b = idx / 10, o = idx % 10;
  int lane = threadIdx.x;      // 64
  float acc = 0.f;
  #pragma unroll
  for(int k = 0; k < 8; k++){
    int h = lane + k*64;
    acc += hid[b*512 + h] * w2[h*10 + o];
  }
  #pragma unroll
  for(int off = 1; off < 64; off <<= 1) acc += __shfl_xor(acc, off);
  if(lane == 0) out[idx] = acc + b2[o];
}

// ---------------------------------------------------------------- launch
extern "C" void kernel_launch(void* const* d_in, const int* in_sizes, int n_in,
                              void* d_out, int out_size, void* d_ws, size_t ws_size,
                              hipStream_t stream)
{
  const float* emb    = (const float*)d_in[1];
  const float* w_ih_f = (const float*)d_in[2];
  const float* w_hh_f = (const float*)d_in[3];
  const float* b_ih_f = (const float*)d_in[4];
  const float* b_hh_f = (const float*)d_in[5];
  const float* w_ih_b = (const float*)d_in[6];
  const float* w_hh_b = (const float*)d_in[7];
  const float* b_ih_b = (const float*)d_in[8];
  const float* b_hh_b = (const float*)d_in[9];
  const float* attn_w = (const float*)d_in[10];
  const float* attn_b = (const float*)d_in[11];
  const float* ctx_w  = (const float*)d_in[12];
  const float* cls_w1 = (const float*)d_in[13];
  const float* cls_b1 = (const float*)d_in[14];
  const float* cls_w2 = (const float*)d_in[15];
  const float* cls_b2 = (const float*)d_in[16];
  float* out = (float*)d_out;

  char* ws = (char*)d_ws;
  size_t off = 0;
  auto alloc = [&](size_t bytes){ void* p = ws + off; off += (bytes + 255) & ~(size_t)255; return p; };
  uint16_t* femb = (uint16_t*)alloc((size_t)MROWS*DIN*2);      // emb bf16, later overlaid by f_out
  uint16_t* wcat = (uint16_t*)alloc((size_t)NC*DIN*2);
  uint16_t* xp   = (uint16_t*)alloc((size_t)MROWS*NC*2);       // blocked layout
  uint16_t* awT  = (uint16_t*)alloc((size_t)1024*1024*2);
  uint4*    wmem = (uint4*)alloc((size_t)2*16*96*64*16);       // 3 MB pre-swizzled W
  unsigned long long* tagbuf = (unsigned long long*)alloc((size_t)2*2*4*16*256*8);  // 1 MB
  float* scraw   = (float*)alloc((size_t)MROWS*4);
  float* wsm     = (float*)alloc((size_t)B_*T_*4);
  float* ctx     = (float*)alloc((size_t)B_*1024*4);
  float* hid     = (float*)alloc((size_t)B_*512*4);

  (void)hipMemsetAsync(tagbuf, 0, (size_t)2*2*4*16*256*8, stream);
  (void)hipMemsetAsync(scraw, 0, (size_t)MROWS*4, stream);

  k_conv_emb<<<16384, 256, 0, stream>>>(emb, femb, (long)MROWS*DIN/8);
  k_conv_wcat<<<12288, 256, 0, stream>>>(w_ih_f, w_ih_b, wcat, NC*DIN);
  k_conv_awt<<<4096, 256, 0, stream>>>(attn_w, awT, 1024*1024);
  k_conv_whh<<<768, 256, 0, stream>>>(w_hh_f, w_hh_b, wmem);

  k_gemm_xp<<<dim3(24,256), 256, 0, stream>>>(femb, wcat, b_ih_f, b_ih_b, xp);

  k_recur<<<128, 768, 0, stream>>>(xp, wmem, b_hh_f, b_hh_b, tagbuf, femb /* = f_out */);

  k_gemm_att<<<dim3(8,256), 256, 0, stream>>>(femb, awT, attn_b, ctx_w, scraw);
  k_softmax<<<64, 256, 0, stream>>>(scraw, wsm);
  k_ctx<<<256, 256, 0, stream>>>(femb, wsm, ctx);
  k_cls1<<<128, 256, 0, stream>>>(ctx, cls_w1, cls_b1, hid);
  k_cls2<<<640, 64, 0, stream>>>(hid, cls_w2, cls_b2, out);
}